// Round 1
// 4505.737 us; speedup vs baseline: 1.9037x; 1.9037x over previous
//
#include <hip/hip_runtime.h>
#include <hip/hip_bf16.h>

#define B_ 64
#define T_ 512
#define D_ 256
#define H_ 1024
#define RING 64          // h-history ring depth
#define PS 260           // partial row stride in floats (8*32 + 4 pad -> bank stride 4)

typedef __attribute__((ext_vector_type(8))) short short8;
typedef __attribute__((ext_vector_type(4))) float floatx4;

__device__ __forceinline__ unsigned short f2bf(float f){
  unsigned u = __builtin_bit_cast(unsigned, f);
  u = (u + 0x7fffu + ((u >> 16) & 1u)) >> 16;
  return (unsigned short)u;
}

__device__ __forceinline__ short8 pack8(floatx4 a, floatx4 b){
  short8 r;
  r[0]=(short)f2bf(a[0]); r[1]=(short)f2bf(a[1]); r[2]=(short)f2bf(a[2]); r[3]=(short)f2bf(a[3]);
  r[4]=(short)f2bf(b[0]); r[5]=(short)f2bf(b[1]); r[6]=(short)f2bf(b[2]); r[7]=(short)f2bf(b[3]);
  return r;
}

__device__ __forceinline__ float sigm(float v){ return 1.f/(1.f+__expf(-v)); }
__device__ __forceinline__ float tanh_f(float v){ return 1.f - 2.f/(1.f+__expf(2.f*v)); }

// Global poll: one wave checks 64 producer counters (packed pairs, coalesced 512B load).
__device__ __forceinline__ void gpoll(const unsigned long long* watch, unsigned tgt0, unsigned tgt1){
  if (!(tgt0 | tgt1)) return;
  long g = 0;
  for (;;){
    unsigned long long v = __hip_atomic_load(watch, __ATOMIC_RELAXED, __HIP_MEMORY_SCOPE_AGENT);
    unsigned v0 = (unsigned)v, v1 = (unsigned)(v >> 32);
    if (__all(v0 >= tgt0 && v1 >= tgt1)) break;
    __builtin_amdgcn_s_sleep(1);
    if (++g > (1L<<22)) break;   // safety valve; never hit in correct runs
  }
}

// LDS spin: zero fabric traffic for non-pollster waves.
__device__ __forceinline__ void lspin(unsigned* flag, unsigned tgt){
  long g = 0;
  while (__hip_atomic_load(flag, __ATOMIC_RELAXED, __HIP_MEMORY_SCOPE_WORKGROUP) < tgt){
    __builtin_amdgcn_s_sleep(1);
    if (++g > (1L<<22)) break;
  }
}

// LAYER 0: K = 256 (x, fp32) + 1024 (h0).  LAYER 1: K = 1024 (h0) + 1024 (h1).
// Block: 512 threads = 8 waves = 8 K-slices; each wave computes all 64 gate rows x 32 batch rows.
// Grid: 256 blocks = 2 layers x 2 batch-halves x 64 column-groups.
template<int LAYER>
__device__ __forceinline__ void run_lstm(
    const float* __restrict__ x,
    const float* __restrict__ Wi, const float* __restrict__ Wh,
    const float* __restrict__ bi, const float* __restrict__ bh,
    unsigned* seq, unsigned short* h0h, unsigned short* h1h, float* h1f,
    int jbase, int j, int half,
    float* partial /*[64][PS]*/, float* c_st /*[32*16]*/, float* biasv /*[64]*/,
    unsigned* rdy /*[2] in LDS*/)
{
  constexpr int KTOT = LAYER ? 2048 : 1280;
  constexpr int KW   = KTOT/8;          // per-k-slice K extent (256 / 160)
  constexpr int NK   = KW/32;           // k-steps per wave (8 / 5)
  constexpr int KA   = LAYER ? 1024 : 256;  // Wi K extent

  const int tid  = threadIdx.x;
  const int wave = tid >> 6;
  const int lane = tid & 63;
  const int ksl  = wave;                // wave == k-slice
  const int n15  = lane & 15;
  const int kq   = (lane >> 4) * 8;

  // ---- one-time: weights -> registers (bf16). 4 n-tiles x NK k-steps per wave.
  short8 bfr[4][NK];
  #pragma unroll
  for (int nt = 0; nt < 4; nt++){
    int n   = nt*16 + n15;
    int row = (n >> 4)*H_ + jbase + (n & 15);
    #pragma unroll
    for (int ks = 0; ks < NK; ks++){
      int k = ksl*KW + ks*32 + kq;
      const float* s = (k < KA) ? (Wi + (size_t)row*KA + k)
                                : (Wh + (size_t)row*H_ + (k - KA));
      bfr[nt][ks] = pack8(*(const floatx4*)s, *(const floatx4*)(s + 4));
    }
  }
  if (tid < 64){
    int col = (tid >> 4)*H_ + jbase + (tid & 15);
    biasv[tid] = bi[col] + bh[col];
  }
  c_st[tid & 511] = 0.f;                 // 512 floats, 512 threads
  if (tid == 0){ rdy[0] = 0u; rdy[1] = 0u; }
  __syncthreads();

  // packed counters: qword per producer block: lo = layer0 seq, hi = layer1 seq
  const unsigned long long* watch = (const unsigned long long*)seq + (half*64 + lane);

  for (int t = 0; t < T_; t++){
    // ---- dataflow sync: 1-2 pollster waves hit global; others spin on LDS.
    if (LAYER == 0){
      if (wave == 0){
        // x-only slice: only ring backpressure (layer-1 consumers of h0 slot t-RING)
        gpoll(watch, 0u, (t >= RING) ? (unsigned)(t - RING + 1) : 0u);
      } else if (wave == 1){
        gpoll(watch, (unsigned)t, 0u);       // peers finished step t-1 (h0[t-1] ready)
        if (lane == 0) __hip_atomic_store(&rdy[0], (unsigned)(t + 1),
                                          __ATOMIC_RELAXED, __HIP_MEMORY_SCOPE_WORKGROUP);
      } else {
        lspin(&rdy[0], (unsigned)(t + 1));
      }
    } else {
      if (wave == 0){
        gpoll(watch, (unsigned)(t + 1), 0u); // layer0 finished step t (h0[t] ready)
        if (lane == 0) __hip_atomic_store(&rdy[0], (unsigned)(t + 1),
                                          __ATOMIC_RELAXED, __HIP_MEMORY_SCOPE_WORKGROUP);
      } else if (wave < 4){
        lspin(&rdy[0], (unsigned)(t + 1));
      } else if (wave == 4){
        gpoll(watch, 0u, (unsigned)t);       // layer1 peers finished t-1 (h1[t-1] ready)
        if (lane == 0) __hip_atomic_store(&rdy[1], (unsigned)(t + 1),
                                          __ATOMIC_RELAXED, __HIP_MEMORY_SCOPE_WORKGROUP);
      } else {
        lspin(&rdy[1], (unsigned)(t + 1));
      }
    }
    __builtin_amdgcn_sched_barrier(0);   // keep h loads below the poll

    floatx4 acc[2][4];
    #pragma unroll
    for (int mt = 0; mt < 2; mt++)
      #pragma unroll
      for (int nt = 0; nt < 4; nt++)
        acc[mt][nt] = (floatx4)0.f;

    const unsigned short* h0t = h0h + (size_t)((LAYER ? t : (t-1)) & (RING-1)) * (B_*H_);
    const unsigned short* h1t = h1h + (size_t)((t-1) & (RING-1)) * (B_*H_);

    #pragma unroll
    for (int ks = 0; ks < NK; ks++){
      const int kb = ksl*KW + ks*32;
      if (kb >= KA && t == 0) continue;   // h[-1] = 0: skip (wave-uniform)
      const int kk = kb + kq;
      short8 afr[2];
      if constexpr (LAYER == 0){
        if (kb < D_){
          #pragma unroll
          for (int mt = 0; mt < 2; mt++){
            const float* xs = x + ((size_t)(half*32 + mt*16 + n15)*T_ + t)*D_ + kk;
            afr[mt] = pack8(*(const floatx4*)xs, *(const floatx4*)(xs + 4));
          }
        } else {
          const unsigned short* base = h0t + (kk - D_);
          #pragma unroll
          for (int mt = 0; mt < 2; mt++)
            afr[mt] = *(const short8*)(base + (size_t)(half*32 + mt*16 + n15)*H_);
        }
      } else {
        const unsigned short* base = (kb < 1024) ? (h0t + kk) : (h1t + (kk - 1024));
        #pragma unroll
        for (int mt = 0; mt < 2; mt++)
          afr[mt] = *(const short8*)(base + (size_t)(half*32 + mt*16 + n15)*H_);
      }
      #pragma unroll
      for (int mt = 0; mt < 2; mt++)
        #pragma unroll
        for (int nt = 0; nt < 4; nt++)
          acc[mt][nt] = __builtin_amdgcn_mfma_f32_16x16x32_bf16(afr[mt], bfr[nt][ks], acc[mt][nt], 0, 0, 0);
    }

    // ---- spill K-slice partials: [n][ksl*32+b] so 4 acc rows are one ds_write_b128
    #pragma unroll
    for (int mt = 0; mt < 2; mt++)
      #pragma unroll
      for (int nt = 0; nt < 4; nt++){
        int n  = nt*16 + n15;
        int b0 = mt*16 + (lane >> 4)*4;
        *(floatx4*)(partial + (size_t)n*PS + ksl*32 + b0) = acc[mt][nt];
      }
    __syncthreads();

    // ---- gate reduction by ALL 512 threads: one (b, jj) each
    {
      int b = tid >> 4, jj = tid & 15;
      float g[4];
      #pragma unroll
      for (int q = 0; q < 4; q++){
        const float* p = partial + (size_t)(q*16 + jj)*PS + b;
        float s = biasv[q*16 + jj];
        #pragma unroll
        for (int ss = 0; ss < 8; ss++) s += p[ss*32];
        g[q] = s;
      }
      float co = c_st[tid];            // tid == b*16 + jj
      float si = sigm(g[0]), sf = sigm(g[1]), tg = tanh_f(g[2]), so = sigm(g[3]);
      float cn = sf*co + si*tg;
      float hn = so*tanh_f(cn);
      c_st[tid] = cn;
      unsigned hb = (unsigned)f2bf(hn);
      unsigned ob = (unsigned)__shfl_xor((int)hb, 1, 64);   // partner jj^1, same b
      if (!(jj & 1)){
        unsigned pk = hb | (ob << 16);
        unsigned short* dst = (LAYER ? h1h : h0h)
                            + (size_t)(t & (RING-1))*(B_*H_)
                            + (size_t)(half*32 + b)*H_ + jbase + jj;
        __hip_atomic_store((unsigned*)dst, pk, __ATOMIC_RELAXED, __HIP_MEMORY_SCOPE_AGENT);
      }
      if (LAYER == 1 && t == T_-1)
        h1f[(size_t)(half*32 + b)*H_ + jbase + jj] = hn;
    }
    __syncthreads();   // all waves drain vmcnt (h stores visible) before the post
    if (tid == 0)
      __hip_atomic_store(seq + (size_t)(half*64 + j)*2 + LAYER, (unsigned)(t + 1),
                         __ATOMIC_RELAXED, __HIP_MEMORY_SCOPE_AGENT);
  }
}

__global__ __launch_bounds__(512, 2) void lstm_pk(
    const float* __restrict__ x,
    const float* __restrict__ Wih0, const float* __restrict__ Whh0,
    const float* __restrict__ bih0, const float* __restrict__ bhh0,
    const float* __restrict__ Wih1, const float* __restrict__ Whh1,
    const float* __restrict__ bih1, const float* __restrict__ bhh1,
    char* __restrict__ ws)
{
  __shared__ __align__(16) float partial[64*PS];   // 66.6 KB
  __shared__ float c_st[512];
  __shared__ float biasv[64];
  __shared__ unsigned rdy[2];

  unsigned* seq       = (unsigned*)ws;                                    // 128 qword pairs (1 KB), packed
  unsigned short* h0h = (unsigned short*)(ws + (1<<20));                  // RING x [64][1024] bf16 (8 MB)
  unsigned short* h1h = (unsigned short*)(ws + (1<<20) + RING*B_*H_*2);   // 8 MB
  float* h1f          = (float*)(ws + (1<<20) + 2*(size_t)RING*B_*H_*2);  // [64][1024] fp32

  const int bid = blockIdx.x;
  if (bid < 128){
    run_lstm<0>(x, Wih0, Whh0, bih0, bhh0, seq, h0h, h1h, h1f,
                (bid & 63)*16, bid & 63, bid >> 6, partial, c_st, biasv, rdy);
  } else {
    const int r = bid - 128;
    run_lstm<1>(x, Wih1, Whh1, bih1, bhh1, seq, h0h, h1h, h1f,
                (r & 63)*16, r & 63, r >> 6, partial, c_st, biasv, rdy);
  }
}

__global__ __launch_bounds__(128) void fc_k(
    const float* __restrict__ h1f, const float* __restrict__ Wfc,
    const float* __restrict__ bfc, float* __restrict__ out)
{
  __shared__ float hv[1024];
  int b = blockIdx.x, c = threadIdx.x;
  for (int i = c; i < 1024; i += 128) hv[i] = h1f[(size_t)b*1024 + i];
  __syncthreads();
  const floatx4* w4 = (const floatx4*)(Wfc + (size_t)c*1024);
  const floatx4* h4 = (const floatx4*)hv;
  float acc = 0.f;
  #pragma unroll 8
  for (int k = 0; k < 256; k++){
    floatx4 wv = w4[k];
    floatx4 hh = h4[k];
    acc += wv[0]*hh[0] + wv[1]*hh[1] + wv[2]*hh[2] + wv[3]*hh[3];
  }
  out[(size_t)b*128 + c] = acc + bfc[c];
}

extern "C" void kernel_launch(void* const* d_in, const int* in_sizes, int n_in,
                              void* d_out, int out_size, void* d_ws, size_t ws_size,
                              hipStream_t stream)
{
  const float* x    = (const float*)d_in[0];
  const float* Wih0 = (const float*)d_in[1];
  const float* Whh0 = (const float*)d_in[2];
  const float* bih0 = (const float*)d_in[3];
  const float* bhh0 = (const float*)d_in[4];
  const float* Wih1 = (const float*)d_in[5];
  const float* Whh1 = (const float*)d_in[6];
  const float* bih1 = (const float*)d_in[7];
  const float* bhh1 = (const float*)d_in[8];
  const float* Wfc  = (const float*)d_in[9];
  const float* bfc  = (const float*)d_in[10];

  // zero only the packed seq region (h ring slots written before first read; h[-1] by predication)
  hipMemsetAsync(d_ws, 0, 128*2*sizeof(unsigned), stream);

  lstm_pk<<<256, 512, 0, stream>>>(x, Wih0, Whh0, bih0, bhh0, Wih1, Whh1, bih1, bhh1, (char*)d_ws);

  const float* h1f = (const float*)((char*)d_ws + (1<<20) + 2*(size_t)RING*B_*H_*2);
  fc_k<<<64, 128, 0, stream>>>(h1f, Wfc, bfc, (float*)d_out);
}

// Round 2
// 3117.456 us; speedup vs baseline: 2.7515x; 1.4453x over previous
//
#include <hip/hip_runtime.h>
#include <hip/hip_bf16.h>

#define B_ 64
#define T_ 512
#define D_ 256
#define H_ 1024
#define RING 64          // h-history ring depth
#define PS 260           // partial row stride in floats (8*32 + 4 pad -> bank stride 4)

typedef __attribute__((ext_vector_type(8))) short short8;
typedef __attribute__((ext_vector_type(4))) float floatx4;

__device__ __forceinline__ unsigned short f2bf(float f){
  unsigned u = __builtin_bit_cast(unsigned, f);
  u = (u + 0x7fffu + ((u >> 16) & 1u)) >> 16;
  return (unsigned short)u;
}

__device__ __forceinline__ short8 pack8(floatx4 a, floatx4 b){
  short8 r;
  r[0]=(short)f2bf(a[0]); r[1]=(short)f2bf(a[1]); r[2]=(short)f2bf(a[2]); r[3]=(short)f2bf(a[3]);
  r[4]=(short)f2bf(b[0]); r[5]=(short)f2bf(b[1]); r[6]=(short)f2bf(b[2]); r[7]=(short)f2bf(b[3]);
  return r;
}

__device__ __forceinline__ float sigm(float v){ return 1.f/(1.f+__expf(-v)); }
__device__ __forceinline__ float tanh_f(float v){ return 1.f - 2.f/(1.f+__expf(2.f*v)); }

// Global poll: one wave checks 64 producer counters (packed pairs, coalesced 512B load).
// No sleep: detect latency is the step-period critical path; pollster traffic is tiny.
__device__ __forceinline__ void gpoll(const unsigned long long* watch, unsigned tgt0, unsigned tgt1){
  if (!(tgt0 | tgt1)) return;
  long g = 0;
  for (;;){
    unsigned long long v = __hip_atomic_load(watch, __ATOMIC_RELAXED, __HIP_MEMORY_SCOPE_AGENT);
    unsigned v0 = (unsigned)v, v1 = (unsigned)(v >> 32);
    if (__all(v0 >= tgt0 && v1 >= tgt1)) break;
    if (++g > (1L<<24)) break;   // safety valve; never hit in correct runs
  }
}

// LDS spin: zero fabric traffic for non-pollster waves.
__device__ __forceinline__ void lspin(unsigned* flag, unsigned tgt){
  long g = 0;
  while (__hip_atomic_load(flag, __ATOMIC_RELAXED, __HIP_MEMORY_SCOPE_WORKGROUP) < tgt){
    if (++g > (1L<<24)) break;
  }
}

// h ring layout: MFMA-fragment tiles.  slot*(64*1024) + jblk*1024 + row*16 + (col&15)  [shorts]
// Producer block j writes one contiguous 1KB run; consumer lane loads are 512B-contiguous
// per 16-lane group (vs 16 scattered 2KB-strided lines with row-major [b][H]).

// LAYER 0: K = 256 (x, fp32) + 1024 (h0).  LAYER 1: K = 1024 (h0) + 1024 (h1).
// Block: 512 threads = 8 waves = 8 K-slices; each wave computes all 64 gate rows x 32 batch rows.
// Grid: 256 blocks = 2 layers x 2 batch-halves x 64 column-groups.
template<int LAYER>
__device__ __forceinline__ void run_lstm(
    const float* __restrict__ x,
    const float* __restrict__ Wi, const float* __restrict__ Wh,
    const float* __restrict__ bi, const float* __restrict__ bh,
    unsigned* seq, unsigned short* h0h, unsigned short* h1h, float* h1f,
    int jbase, int j, int half,
    float* partial /*[64][PS]*/, float* c_st /*[32*16]*/, float* biasv /*[64]*/,
    unsigned* rdy /*[2] in LDS*/)
{
  constexpr int KTOT = LAYER ? 2048 : 1280;
  constexpr int KW   = KTOT/8;          // per-k-slice K extent (256 / 160)
  constexpr int NK   = KW/32;           // k-steps per wave (8 / 5)
  constexpr int KA   = LAYER ? 1024 : 256;  // Wi K extent

  const int tid  = threadIdx.x;
  const int wave = tid >> 6;
  const int lane = tid & 63;
  const int ksl  = wave;                // wave == k-slice
  const int n15  = lane & 15;
  const int kq   = (lane >> 4) * 8;

  // ---- one-time: weights -> registers (bf16). 4 n-tiles x NK k-steps per wave.
  short8 bfr[4][NK];
  #pragma unroll
  for (int nt = 0; nt < 4; nt++){
    int n   = nt*16 + n15;
    int row = (n >> 4)*H_ + jbase + (n & 15);
    #pragma unroll
    for (int ks = 0; ks < NK; ks++){
      int k = ksl*KW + ks*32 + kq;
      const float* s = (k < KA) ? (Wi + (size_t)row*KA + k)
                                : (Wh + (size_t)row*H_ + (k - KA));
      bfr[nt][ks] = pack8(*(const floatx4*)s, *(const floatx4*)(s + 4));
    }
  }
  if (tid < 64){
    int col = (tid >> 4)*H_ + jbase + (tid & 15);
    biasv[tid] = bi[col] + bh[col];
  }
  c_st[tid & 511] = 0.f;
  if (tid == 0){ rdy[0] = 0u; rdy[1] = 0u; }
  __syncthreads();

  // packed counters: qword per producer block: lo = layer0 seq, hi = layer1 seq
  const unsigned long long* watch = (const unsigned long long*)seq + (half*64 + lane);

  for (int t = 0; t < T_; t++){
    // ---- L0: issue raw x loads BEFORE the poll (x[t] has no recurrence dep).
    // Keep raw fp32 in regs through the poll; pack after.  Latency hides under the wait.
    floatx4 xraw[LAYER ? 1 : NK][2][2];
    if constexpr (LAYER == 0){
      #pragma unroll
      for (int ks = 0; ks < NK; ks++){
        const int kb = ksl*KW + ks*32;
        if (kb < D_){
          const int kk = kb + kq;
          #pragma unroll
          for (int mt = 0; mt < 2; mt++){
            const float* xs = x + ((size_t)(half*32 + mt*16 + n15)*T_ + t)*D_ + kk;
            xraw[ks][mt][0] = *(const floatx4*)xs;
            xraw[ks][mt][1] = *(const floatx4*)(xs + 4);
          }
        }
      }
    }

    // ---- dataflow sync: 1-2 pollster waves hit global; others spin on LDS.
    if (LAYER == 0){
      if (wave == 0){
        // x-only slice: only ring backpressure (layer-1 consumers of h0 slot t-RING)
        gpoll(watch, 0u, (t >= RING) ? (unsigned)(t - RING + 1) : 0u);
      } else if (wave == 1){
        gpoll(watch, (unsigned)t, 0u);       // peers finished step t-1 (h0[t-1] ready)
        if (lane == 0) __hip_atomic_store(&rdy[0], (unsigned)(t + 1),
                                          __ATOMIC_RELAXED, __HIP_MEMORY_SCOPE_WORKGROUP);
      } else {
        lspin(&rdy[0], (unsigned)(t + 1));
      }
    } else {
      if (wave == 0){
        gpoll(watch, (unsigned)(t + 1), 0u); // layer0 finished step t (h0[t] ready)
        if (lane == 0) __hip_atomic_store(&rdy[0], (unsigned)(t + 1),
                                          __ATOMIC_RELAXED, __HIP_MEMORY_SCOPE_WORKGROUP);
      } else if (wave < 4){
        lspin(&rdy[0], (unsigned)(t + 1));
      } else if (wave == 4){
        gpoll(watch, 0u, (unsigned)t);       // layer1 peers finished t-1 (h1[t-1] ready)
        if (lane == 0) __hip_atomic_store(&rdy[1], (unsigned)(t + 1),
                                          __ATOMIC_RELAXED, __HIP_MEMORY_SCOPE_WORKGROUP);
      } else {
        lspin(&rdy[1], (unsigned)(t + 1));
      }
    }
    __builtin_amdgcn_sched_barrier(0);   // keep h loads below the poll

    floatx4 acc[2][4];
    #pragma unroll
    for (int mt = 0; mt < 2; mt++)
      #pragma unroll
      for (int nt = 0; nt < 4; nt++)
        acc[mt][nt] = (floatx4)0.f;

    const unsigned short* h0t = h0h + ((size_t)((LAYER ? t : (t-1)) & (RING-1)) << 16);
    const unsigned short* h1t = h1h + ((size_t)((t-1) & (RING-1)) << 16);

    #pragma unroll
    for (int ks = 0; ks < NK; ks++){
      const int kb = ksl*KW + ks*32;
      if (kb >= KA && t == 0) continue;   // h[-1] = 0: skip (wave-uniform)
      const int kk = kb + kq;
      short8 afr[2];
      if constexpr (LAYER == 0){
        if (kb < D_){
          #pragma unroll
          for (int mt = 0; mt < 2; mt++)
            afr[mt] = pack8(xraw[ks][mt][0], xraw[ks][mt][1]);
        } else {
          const int hk = kk - D_;
          const unsigned short* p = h0t + ((hk >> 4) << 10) + (hk & 15);
          #pragma unroll
          for (int mt = 0; mt < 2; mt++)
            afr[mt] = *(const short8*)(p + ((half*32 + mt*16 + n15) << 4));
        }
      } else {
        const int hk = (kb < 1024) ? kk : (kk - 1024);
        const unsigned short* sb = (kb < 1024) ? h0t : h1t;
        const unsigned short* p = sb + ((hk >> 4) << 10) + (hk & 15);
        #pragma unroll
        for (int mt = 0; mt < 2; mt++)
          afr[mt] = *(const short8*)(p + ((half*32 + mt*16 + n15) << 4));
      }
      #pragma unroll
      for (int mt = 0; mt < 2; mt++)
        #pragma unroll
        for (int nt = 0; nt < 4; nt++)
          acc[mt][nt] = __builtin_amdgcn_mfma_f32_16x16x32_bf16(afr[mt], bfr[nt][ks], acc[mt][nt], 0, 0, 0);
    }

    // ---- spill K-slice partials: [n][ksl*32+b] so 4 acc rows are one ds_write_b128
    #pragma unroll
    for (int mt = 0; mt < 2; mt++)
      #pragma unroll
      for (int nt = 0; nt < 4; nt++){
        int n  = nt*16 + n15;
        int b0 = mt*16 + (lane >> 4)*4;
        *(floatx4*)(partial + (size_t)n*PS + ksl*32 + b0) = acc[mt][nt];
      }
    __syncthreads();

    // ---- gate reduction by ALL 512 threads: one (b, jj) each
    {
      int b = tid >> 4, jj = tid & 15;
      float g[4];
      #pragma unroll
      for (int q = 0; q < 4; q++){
        const float* p = partial + (size_t)(q*16 + jj)*PS + b;
        float s = biasv[q*16 + jj];
        #pragma unroll
        for (int ss = 0; ss < 8; ss++) s += p[ss*32];
        g[q] = s;
      }
      float co = c_st[tid];            // tid == b*16 + jj
      float si = sigm(g[0]), sf = sigm(g[1]), tg = tanh_f(g[2]), so = sigm(g[3]);
      float cn = sf*co + si*tg;
      float hn = so*tanh_f(cn);
      c_st[tid] = cn;
      unsigned hb = (unsigned)f2bf(hn);
      unsigned ob = (unsigned)__shfl_xor((int)hb, 1, 64);   // partner jj^1, same b
      if (!(jj & 1)){
        unsigned pk = hb | (ob << 16);
        // tile layout store: contiguous 1KB per block (addr == slot + j*1024 + tid)
        unsigned short* dst = (LAYER ? h1h : h0h)
                            + ((size_t)(t & (RING-1)) << 16)
                            + ((size_t)j << 10) + ((size_t)(half*32 + b) << 4) + jj;
        __hip_atomic_store((unsigned*)dst, pk, __ATOMIC_RELAXED, __HIP_MEMORY_SCOPE_AGENT);
      }
      if (LAYER == 1 && t == T_-1)
        h1f[(size_t)(half*32 + b)*H_ + jbase + jj] = hn;
    }
    __syncthreads();   // all waves drain vmcnt (h stores visible) before the post
    if (tid == 0)
      __hip_atomic_store(seq + (size_t)(half*64 + j)*2 + LAYER, (unsigned)(t + 1),
                         __ATOMIC_RELAXED, __HIP_MEMORY_SCOPE_AGENT);
  }
}

__global__ __launch_bounds__(512, 2) void lstm_pk(
    const float* __restrict__ x,
    const float* __restrict__ Wih0, const float* __restrict__ Whh0,
    const float* __restrict__ bih0, const float* __restrict__ bhh0,
    const float* __restrict__ Wih1, const float* __restrict__ Whh1,
    const float* __restrict__ bih1, const float* __restrict__ bhh1,
    char* __restrict__ ws)
{
  __shared__ __align__(16) float partial[64*PS];   // 66.6 KB
  __shared__ float c_st[512];
  __shared__ float biasv[64];
  __shared__ unsigned rdy[2];

  unsigned* seq       = (unsigned*)ws;                                    // 128 qword pairs (1 KB), packed
  unsigned short* h0h = (unsigned short*)(ws + (1<<20));                  // RING x 128KB tiles (8 MB)
  unsigned short* h1h = (unsigned short*)(ws + (1<<20) + RING*B_*H_*2);   // 8 MB
  float* h1f          = (float*)(ws + (1<<20) + 2*(size_t)RING*B_*H_*2);  // [64][1024] fp32

  const int bid = blockIdx.x;
  if (bid < 128){
    run_lstm<0>(x, Wih0, Whh0, bih0, bhh0, seq, h0h, h1h, h1f,
                (bid & 63)*16, bid & 63, bid >> 6, partial, c_st, biasv, rdy);
  } else {
    const int r = bid - 128;
    run_lstm<1>(x, Wih1, Whh1, bih1, bhh1, seq, h0h, h1h, h1f,
                (r & 63)*16, r & 63, r >> 6, partial, c_st, biasv, rdy);
  }
}

__global__ __launch_bounds__(128) void fc_k(
    const float* __restrict__ h1f, const float* __restrict__ Wfc,
    const float* __restrict__ bfc, float* __restrict__ out)
{
  __shared__ float hv[1024];
  int b = blockIdx.x, c = threadIdx.x;
  for (int i = c; i < 1024; i += 128) hv[i] = h1f[(size_t)b*1024 + i];
  __syncthreads();
  const floatx4* w4 = (const floatx4*)(Wfc + (size_t)c*1024);
  const floatx4* h4 = (const floatx4*)hv;
  float acc = 0.f;
  #pragma unroll 8
  for (int k = 0; k < 256; k++){
    floatx4 wv = w4[k];
    floatx4 hh = h4[k];
    acc += wv[0]*hh[0] + wv[1]*hh[1] + wv[2]*hh[2] + wv[3]*hh[3];
  }
  out[(size_t)b*128 + c] = acc + bfc[c];
}

extern "C" void kernel_launch(void* const* d_in, const int* in_sizes, int n_in,
                              void* d_out, int out_size, void* d_ws, size_t ws_size,
                              hipStream_t stream)
{
  const float* x    = (const float*)d_in[0];
  const float* Wih0 = (const float*)d_in[1];
  const float* Whh0 = (const float*)d_in[2];
  const float* bih0 = (const float*)d_in[3];
  const float* bhh0 = (const float*)d_in[4];
  const float* Wih1 = (const float*)d_in[5];
  const float* Whh1 = (const float*)d_in[6];
  const float* bih1 = (const float*)d_in[7];
  const float* bhh1 = (const float*)d_in[8];
  const float* Wfc  = (const float*)d_in[9];
  const float* bfc  = (const float*)d_in[10];

  // zero only the packed seq region (h ring slots written before first read; h[-1] by predication)
  hipMemsetAsync(d_ws, 0, 128*2*sizeof(unsigned), stream);

  lstm_pk<<<256, 512, 0, stream>>>(x, Wih0, Whh0, bih0, bhh0, Wih1, Whh1, bih1, bhh1, (char*)d_ws);

  const float* h1f = (const float*)((char*)d_ws + (1<<20) + 2*(size_t)RING*B_*H_*2);
  fc_k<<<64, 128, 0, stream>>>(h1f, Wfc, bfc, (float*)d_out);
}